// Round 12
// baseline (135.153 us; speedup 1.0000x reference)
//
#include <hip/hip_runtime.h>

// TopologyNetwork: B=1024, N=5000, K=16, 9 levels.
// R12 = R9 fused LDS ping-pong + DUAL-COPY bank balancing:
//  - each activation buffer stored twice in LDS; copy B at +TN rows =
//    +40000 B = +16 banks -> bank-pair class flips by +8 (5000%16==8).
//  - at pack time, per k-step, conjugate class pairs {c,c+8} are balanced
//    exactly across the wave via ballot+rank parity -> per-step max bank
//    load ~ceil(n_pair/2) instead of random max ~9.
//  - packed edge u32 = (s + b*5000) | f16(w)<<16; kernel addr = (e&0x3fff)<<3.
//  - pe layout [l][panel][lane][k]: each lane's 16 edges = 64 B contiguous
//    -> 4x dwordx4 loads per node instead of 16 dwords.
//  - LDS = 2 ping x 2 copies x 40000 B = 160000 B (fits 160 KiB).

#define TB 1024
#define TN 5000
#define TK 16
#define TLV 9
#define CPG 4                   // f16 cols per group (8 B per node-row)
#define NG  (TB / CPG)          // 256 col-groups = grid
#define LT  1024                // threads per block (16 waves)
#define NPANEL ((TN + 63) / 64) // 79 panels of 64 nodes
#define PEL (NPANEL * TK * 64)  // u32 per level in packed-edge array

typedef unsigned int u32;
typedef unsigned short u16;
typedef unsigned long long u64;
typedef _Float16 h2 __attribute__((ext_vector_type(2)));

__device__ __forceinline__ h2 u2h(u32 v) { return __builtin_bit_cast(h2, v); }
__device__ __forceinline__ u32 h2u(h2 h) { return __builtin_bit_cast(u32, h); }
__device__ __forceinline__ u32 packf(float a, float b) {
    h2 h; h.x = (_Float16)a; h.y = (_Float16)b;
    return h2u(h);
}

// ---- pack + balance edges ----
// idx i32 + w f32 [l][n][k] -> pe u32 [l][panel][lane][k]
// per k-step: balance conjugate bank-class pairs {c, c+8} across the wave.
__global__ __launch_bounds__(256) void k_pack(
    const int* __restrict__ idx, const float* __restrict__ w,
    u32* __restrict__ pe)
{
    const int wid  = (blockIdx.x * 256 + threadIdx.x) >> 6;  // global wave id
    const int lane = threadIdx.x & 63;
    const int l = wid / NPANEL;
    const int p = wid % NPANEL;
    if (l >= TLV) return;
    const int n = p * 64 + lane;
    const bool valid = (n < TN);

    u32 sv[TK];
    u32 hw[TK];
    {
        const size_t base = ((size_t)l * TN + (valid ? n : 0)) * TK;
        #pragma unroll
        for (int k = 0; k < TK; ++k) {
            sv[k] = valid ? (u32)idx[base + k] : 0u;
            h2 h; h.x = (_Float16)(valid ? w[base + k] : 0.0f); h.y = (_Float16)0.0f;
            hw[k] = h2u(h);
        }
    }

    const u64 lt_mask = (lane == 0) ? 0ull : (~0ull >> (64 - lane));
    u32 ev[TK];
    #pragma unroll
    for (int k = 0; k < TK; ++k) {
        const u32 c  = sv[k] & 15u;      // bank-pair class of copy A
        const u32 pr = c & 7u;           // conjugate-pair id
        const u32 hi = c >> 3;           // which side of the pair copy A is
        int rank = 0;
        #pragma unroll
        for (u32 q = 0; q < 8; ++q) {
            const u64 m = __ballot(pr == q);
            if (pr == q) rank = __popcll(m & lt_mask);
        }
        const u32 tgt = (u32)(rank & 1);         // desired side
        const u32 b   = (tgt != hi) ? 1u : 0u;   // copy bit
        ev[k] = (sv[k] + b * (u32)TN) | (hw[k] << 16);
    }

    // [panel][lane][k]: 64 B contiguous per lane -> coalesced wide stores
    u32* dst = pe + (size_t)l * PEL + (size_t)p * (TK * 64) + lane * TK;
    #pragma unroll
    for (int k = 0; k < TK; ++k) dst[k] = ev[k];
}

// ---- fused: transpose-in + 9 levels in LDS + transpose-out ----
__global__ __launch_bounds__(LT) void k_fused(
    const float* __restrict__ x,      // [B,N]
    float* __restrict__ out,          // [B,N]
    const u32* __restrict__ pe,       // [LV][PEL]
    const float* __restrict__ biases) // [LV][TN]
{
    __shared__ uint2 buf[2][2 * TN];  // [ping][copyA | copyB] = 160000 B
    const int g = blockIdx.x;
    const int t = threadIdx.x;

    // stage x cols g*4..g*4+3 as f16 rows (both copies)
    {
        const float* xp0 = x + (size_t)(g * CPG + 0) * TN;
        const float* xp1 = x + (size_t)(g * CPG + 1) * TN;
        const float* xp2 = x + (size_t)(g * CPG + 2) * TN;
        const float* xp3 = x + (size_t)(g * CPG + 3) * TN;
        for (int n = t; n < TN; n += LT) {
            uint2 v;
            v.x = packf(xp0[n], xp1[n]);
            v.y = packf(xp2[n], xp3[n]);
            buf[0][n]      = v;
            buf[0][TN + n] = v;
        }
    }
    __syncthreads();

    int cur = 0;
    for (int l = 0; l < TLV; ++l) {
        const u32*   ep_l = pe + (size_t)l * PEL;
        const float* b_l  = biases + (size_t)l * TN;
        const char*  base = reinterpret_cast<const char*>(buf[cur]);
        for (int n = t; n < TN; n += LT) {
            const uint4* ep = reinterpret_cast<const uint4*>(
                ep_l + (size_t)(n >> 6) * (TK * 64) + (n & 63) * TK);
            const uint4 e0 = ep[0];
            const uint4 e1 = ep[1];
            const uint4 e2 = ep[2];
            const uint4 e3 = ep[3];
            const u32 es[TK] = {e0.x, e0.y, e0.z, e0.w,
                                e1.x, e1.y, e1.z, e1.w,
                                e2.x, e2.y, e2.z, e2.w,
                                e3.x, e3.y, e3.z, e3.w};

            const float bvf = b_l[n];
            h2 bb; bb.x = (_Float16)bvf; bb.y = (_Float16)bvf;
            h2 a01 = bb, a23 = bb;

            #pragma unroll
            for (int k = 0; k < TK; ++k) {
                const u32 e  = es[k];
                const u32 off = (e & 0x3fffu) << 3;        // byte offset (covers both copies)
                const h2 w2 = u2h(__builtin_amdgcn_perm(e, e, 0x03020302u));
                const uint2 av = *reinterpret_cast<const uint2*>(base + off);
                a01 = w2 * u2h(av.x) + a01;                // v_pk_fma_f16
                a23 = w2 * u2h(av.y) + a23;
            }

            // LeakyReLU(0.1) = max(x, 0.1*x)
            h2 tenth; tenth.x = (_Float16)0.1f; tenth.y = (_Float16)0.1f;
            a01 = __builtin_elementwise_max(a01, a01 * tenth);
            a23 = __builtin_elementwise_max(a23, a23 * tenth);

            uint2 r; r.x = h2u(a01); r.y = h2u(a23);
            buf[cur ^ 1][n]      = r;
            buf[cur ^ 1][TN + n] = r;
        }
        __syncthreads();
        cur ^= 1;
    }

    // write out cols g*4..g*4+3
    {
        float* op0 = out + (size_t)(g * CPG + 0) * TN;
        float* op1 = out + (size_t)(g * CPG + 1) * TN;
        float* op2 = out + (size_t)(g * CPG + 2) * TN;
        float* op3 = out + (size_t)(g * CPG + 3) * TN;
        for (int n = t; n < TN; n += LT) {
            const uint2 v = buf[cur][n];
            h2 h;
            h = u2h(v.x); op0[n] = (float)h.x; op1[n] = (float)h.y;
            h = u2h(v.y); op2[n] = (float)h.x; op3[n] = (float)h.y;
        }
    }
}

extern "C" void kernel_launch(void* const* d_in, const int* in_sizes, int n_in,
                              void* d_out, int out_size, void* d_ws, size_t ws_size,
                              hipStream_t stream)
{
    const float* x       = (const float*)d_in[0];   // [B,N]
    const int*   src_idx = (const int*)  d_in[1];   // [LV,N,K]
    const float* weights = (const float*)d_in[2];   // [LV,N,K]
    const float* biases  = (const float*)d_in[3];   // [LV,N]
    float* out = (float*)d_out;                     // [B,N]

    u32* pe = (u32*)d_ws;                           // [LV][PEL] = 2.91 MB

    // pack + balance edges: one wave per (level, panel)
    {
        const int nwaves  = TLV * NPANEL;           // 711
        const int nblocks = (nwaves + 3) / 4;       // 4 waves per 256-thr block
        hipLaunchKernelGGL(k_pack, dim3(nblocks), dim3(256), 0, stream,
                           src_idx, weights, pe);
    }
    // fused 9-level evaluation
    hipLaunchKernelGGL(k_fused, dim3(NG), dim3(LT), 0, stream,
                       x, out, pe, biases);
}

// Round 13
// 127.440 us; speedup vs baseline: 1.0605x; 1.0605x over previous
//
#include <hip/hip_runtime.h>

// TopologyNetwork: B=1024, N=5000, K=16, 9 levels.
// R13 = R11's fused kernel (best measured: 57.7 us) + cheap coalesced pack:
//  - k_pack: pure elementwise pe[j] = (idx[j]*8 | f16(w[j])<<16), [l][n][k]
//    layout -> reads AND writes perfectly coalesced (R11's per-lane strided
//    idx reads cost ~15 us in wasted cachelines; sort/balance experiments
//    R10-R12 showed conflict scheduling tops out at -14%, net <= 0).
//  - k_fused: fully-fused 9 levels ping-ponging in 2 x 40000 B LDS, one
//    block per 4-column group (grid 256 = 1/CU, 16 waves). Edge loads are
//    4 x uint4 per node (64 B contiguous). Gather = ds_read_b64 at byte
//    offset (e & 0xffff) = s*8. Packed f16x2 FMA accumulate.

#define TB 1024
#define TN 5000
#define TK 16
#define TLV 9
#define CPG 4                   // f16 cols per group (8 B per node-row)
#define NG  (TB / CPG)          // 256 col-groups = grid
#define LT  1024                // threads per block (16 waves)
#define PEL (TN * TK)           // u32 per level in packed-edge array

typedef unsigned int u32;
typedef unsigned short u16;
typedef _Float16 h2 __attribute__((ext_vector_type(2)));

__device__ __forceinline__ h2 u2h(u32 v) { return __builtin_bit_cast(h2, v); }
__device__ __forceinline__ u32 h2u(h2 h) { return __builtin_bit_cast(u32, h); }
__device__ __forceinline__ u32 packf(float a, float b) {
    h2 h; h.x = (_Float16)a; h.y = (_Float16)b;
    return h2u(h);
}

// ---- pack edges: idx i32 + w f32 [l][n][k] -> pe u32 [l][n][k] ----
// low16 = s*8 (LDS byte offset), high16 = f16(w). Fully coalesced.
__global__ __launch_bounds__(256) void k_pack(
    const int* __restrict__ idx, const float* __restrict__ w,
    u32* __restrict__ pe)
{
    const int j = blockIdx.x * 256 + threadIdx.x;
    if (j < TLV * TN * TK) {
        const u32 s = (u32)idx[j];
        h2 hw; hw.x = (_Float16)w[j]; hw.y = (_Float16)0.0f;
        pe[j] = (s * 8u) | (h2u(hw) << 16);
    }
}

// ---- fused: transpose-in + 9 levels in LDS + transpose-out ----
__global__ __launch_bounds__(LT) void k_fused(
    const float* __restrict__ x,      // [B,N]
    float* __restrict__ out,          // [B,N]
    const u32* __restrict__ pe,       // [LV][TN][TK]
    const float* __restrict__ biases) // [LV][TN]
{
    __shared__ uint2 buf[2][TN];      // 2 x 40000 B ping-pong
    const int g = blockIdx.x;
    const int t = threadIdx.x;

    // stage x cols g*4..g*4+3 as f16 rows
    {
        const float* xp0 = x + (size_t)(g * CPG + 0) * TN;
        const float* xp1 = x + (size_t)(g * CPG + 1) * TN;
        const float* xp2 = x + (size_t)(g * CPG + 2) * TN;
        const float* xp3 = x + (size_t)(g * CPG + 3) * TN;
        for (int n = t; n < TN; n += LT) {
            uint2 v;
            v.x = packf(xp0[n], xp1[n]);
            v.y = packf(xp2[n], xp3[n]);
            buf[0][n] = v;
        }
    }
    __syncthreads();

    int cur = 0;
    for (int l = 0; l < TLV; ++l) {
        const u32*   ep_l = pe + (size_t)l * PEL;
        const float* b_l  = biases + (size_t)l * TN;
        const char*  base = reinterpret_cast<const char*>(buf[cur]);
        for (int n = t; n < TN; n += LT) {
            // 16 edges of node n: 64 B contiguous -> 4x dwordx4
            const uint4* ep = reinterpret_cast<const uint4*>(ep_l + (size_t)n * TK);
            const uint4 e0 = ep[0];
            const uint4 e1 = ep[1];
            const uint4 e2 = ep[2];
            const uint4 e3 = ep[3];
            const u32 es[TK] = {e0.x, e0.y, e0.z, e0.w,
                                e1.x, e1.y, e1.z, e1.w,
                                e2.x, e2.y, e2.z, e2.w,
                                e3.x, e3.y, e3.z, e3.w};

            const float bvf = b_l[n];
            h2 bb; bb.x = (_Float16)bvf; bb.y = (_Float16)bvf;
            h2 a01 = bb, a23 = bb;

            #pragma unroll
            for (int k = 0; k < TK; ++k) {
                const u32 e   = es[k];
                const u32 off = e & 0xffffu;               // s*8 byte offset
                const h2 w2 = u2h(__builtin_amdgcn_perm(e, e, 0x03020302u));
                const uint2 av = *reinterpret_cast<const uint2*>(base + off);
                a01 = w2 * u2h(av.x) + a01;                // v_pk_fma_f16
                a23 = w2 * u2h(av.y) + a23;
            }

            // LeakyReLU(0.1) = max(x, 0.1*x)
            h2 tenth; tenth.x = (_Float16)0.1f; tenth.y = (_Float16)0.1f;
            a01 = __builtin_elementwise_max(a01, a01 * tenth);
            a23 = __builtin_elementwise_max(a23, a23 * tenth);

            uint2 r; r.x = h2u(a01); r.y = h2u(a23);
            buf[cur ^ 1][n] = r;
        }
        __syncthreads();
        cur ^= 1;
    }

    // write out cols g*4..g*4+3
    {
        float* op0 = out + (size_t)(g * CPG + 0) * TN;
        float* op1 = out + (size_t)(g * CPG + 1) * TN;
        float* op2 = out + (size_t)(g * CPG + 2) * TN;
        float* op3 = out + (size_t)(g * CPG + 3) * TN;
        for (int n = t; n < TN; n += LT) {
            const uint2 v = buf[cur][n];
            h2 h;
            h = u2h(v.x); op0[n] = (float)h.x; op1[n] = (float)h.y;
            h = u2h(v.y); op2[n] = (float)h.x; op3[n] = (float)h.y;
        }
    }
}

extern "C" void kernel_launch(void* const* d_in, const int* in_sizes, int n_in,
                              void* d_out, int out_size, void* d_ws, size_t ws_size,
                              hipStream_t stream)
{
    const float* x       = (const float*)d_in[0];   // [B,N]
    const int*   src_idx = (const int*)  d_in[1];   // [LV,N,K]
    const float* weights = (const float*)d_in[2];   // [LV,N,K]
    const float* biases  = (const float*)d_in[3];   // [LV,N]
    float* out = (float*)d_out;                     // [B,N]

    u32* pe = (u32*)d_ws;                           // [LV][TN][TK] = 2.88 MB

    // pack edges (elementwise, fully coalesced)
    {
        const int ne = TLV * TN * TK;
        hipLaunchKernelGGL(k_pack, dim3((ne + 255) / 256), dim3(256), 0, stream,
                           src_idx, weights, pe);
    }
    // fused 9-level evaluation
    hipLaunchKernelGGL(k_fused, dim3(NG), dim3(LT), 0, stream,
                       x, out, pe, biases);
}